// Round 1
// baseline (1560.887 us; speedup 1.0000x reference)
//
#include <hip/hip_runtime.h>
#include <math.h>

#define NB 2
#define NH 16
#define LSEQ 2048
#define DD 64

// ---------------- Kernel 1: QK (reshaped-K) + mask + softmax over HEAD axis ----
// score_raw[b,h,i,j] = (1/8) * sum_d q[b,h,i,d] * kview[b,h][d][j]
//   where kview[b,h] is k's (b,h) block reinterpreted as [64][2048] row-major.
// Then: masked (mask[b,i,j]==0) -> -1e12 -> softmax over h -> exactly 1/16.
// Block: 256 threads, tile = 16 i x 64 j, all 16 heads in registers per thread.
#define BQ 16
#define BJ 64

__global__ __launch_bounds__(256) void qk_softmax_kernel(
    const float* __restrict__ q, const float* __restrict__ k,
    const int* __restrict__ mask, float* __restrict__ score)
{
    __shared__ float qs[BQ][DD];   // 16x64 = 4 KB
    __shared__ float ks[DD][BJ];   // 64x64 = 16 KB

    const int tid = threadIdx.x;
    const int j0  = blockIdx.x * BJ;
    const int i0  = blockIdx.y * BQ;
    const int b   = blockIdx.z;

    const int jl = (tid & 31) * 2;   // 2 consecutive j per thread
    const int ig = tid >> 5;         // 0..7 -> 2 i rows per thread
    const int ia = ig * 2;
    const int ib = ia + 1;

    float acc[NH][2][2];
    #pragma unroll
    for (int h = 0; h < NH; ++h)
        for (int r = 0; r < 2; ++r)
            for (int c = 0; c < 2; ++c) acc[h][r][c] = 0.f;

    #pragma unroll
    for (int h = 0; h < NH; ++h) {
        const float* qb = q + ((size_t)(b * NH + h) * LSEQ + i0) * DD;
        const float* kb = k + (size_t)(b * NH + h) * LSEQ * DD;  // viewed [64][2048]

        // stage q tile: 16x64
        #pragma unroll
        for (int idx = tid; idx < BQ * DD; idx += 256)
            qs[idx >> 6][idx & 63] = qb[(size_t)(idx >> 6) * DD + (idx & 63)];
        // stage k tile (reshaped view): rows d, cols j0..j0+63
        #pragma unroll
        for (int idx = tid; idx < DD * BJ; idx += 256) {
            int d = idx >> 6, c = idx & 63;
            ks[d][c] = kb[(size_t)d * LSEQ + j0 + c];
        }
        __syncthreads();

        #pragma unroll 8
        for (int d = 0; d < DD; d += 2) {
            float2 k0 = *(const float2*)&ks[d][jl];
            float2 k1 = *(const float2*)&ks[d + 1][jl];
            float2 qa = *(const float2*)&qs[ia][d];
            float2 qc = *(const float2*)&qs[ib][d];
            acc[h][0][0] += qa.x * k0.x + qa.y * k1.x;
            acc[h][0][1] += qa.x * k0.y + qa.y * k1.y;
            acc[h][1][0] += qc.x * k0.x + qc.y * k1.x;
            acc[h][1][1] += qc.x * k0.y + qc.y * k1.y;
        }
        __syncthreads();
    }

    // epilogue: scale, mask, softmax over h, store
    const float scale = 0.125f;  // 1/sqrt(64)
    #pragma unroll
    for (int r = 0; r < 2; ++r) {
        const int i = i0 + ia + r;
        const int2 mv = *(const int2*)&mask[((size_t)b * LSEQ + i) * LSEQ + j0 + jl];
        #pragma unroll
        for (int c = 0; c < 2; ++c) {
            const int m = (c == 0) ? mv.x : mv.y;
            if (m == 0) {
                #pragma unroll
                for (int h = 0; h < NH; ++h) acc[h][r][c] = 0.0625f;
            } else {
                float mx = acc[0][r][c];
                #pragma unroll
                for (int h = 1; h < NH; ++h) mx = fmaxf(mx, acc[h][r][c]);
                float sum = 0.f;
                #pragma unroll
                for (int h = 0; h < NH; ++h) {
                    float e = __expf(scale * (acc[h][r][c] - mx));
                    acc[h][r][c] = e;
                    sum += e;
                }
                float inv = 1.0f / sum;
                #pragma unroll
                for (int h = 0; h < NH; ++h) acc[h][r][c] *= inv;
            }
        }
        #pragma unroll
        for (int h = 0; h < NH; ++h) {
            float2 st;
            st.x = acc[h][r][0];
            st.y = acc[h][r][1];
            *(float2*)&score[(((size_t)(b * NH + h)) * LSEQ + i) * LSEQ + j0 + jl] = st;
        }
    }
}

// ---------------- Kernel 2: out = score @ v  (per (b,h): [2048x2048]@[2048x64])
#define TI2 64
#define TJ2 32

__global__ __launch_bounds__(256) void pv_kernel(
    const float* __restrict__ score, const float* __restrict__ v,
    float* __restrict__ out)
{
    __shared__ float s_tile[TI2][TJ2 + 1];  // +1 pad: kill broadcast bank conflict
    __shared__ float v_tile[TJ2][DD];       // float4-aligned rows

    const int tid = threadIdx.x;
    const int i0  = blockIdx.x * TI2;
    const int bh  = blockIdx.z * NH + blockIdx.y;

    const float* sb = score + (size_t)bh * LSEQ * LSEQ;
    const float* vb = v + (size_t)bh * LSEQ * DD;
    float* ob = out + (size_t)bh * LSEQ * DD;

    const int dg = tid & 15;   // d = dg*4 .. dg*4+3
    const int ig = tid >> 4;   // i = ig*4 .. ig*4+3

    float4 acc[4];
    #pragma unroll
    for (int ii = 0; ii < 4; ++ii) acc[ii] = make_float4(0.f, 0.f, 0.f, 0.f);

    for (int jt = 0; jt < LSEQ; jt += TJ2) {
        #pragma unroll
        for (int idx = tid; idx < TI2 * TJ2; idx += 256) {
            int r = idx >> 5, c = idx & 31;
            s_tile[r][c] = sb[(size_t)(i0 + r) * LSEQ + jt + c];
        }
        #pragma unroll
        for (int idx = tid; idx < TJ2 * DD; idx += 256) {
            int r = idx >> 6, c = idx & 63;
            v_tile[r][c] = vb[(size_t)(jt + r) * DD + c];
        }
        __syncthreads();

        #pragma unroll 8
        for (int jj = 0; jj < TJ2; ++jj) {
            float4 vv = *(const float4*)&v_tile[jj][dg * 4];
            #pragma unroll
            for (int ii = 0; ii < 4; ++ii) {
                float sv = s_tile[ig * 4 + ii][jj];
                acc[ii].x += sv * vv.x;
                acc[ii].y += sv * vv.y;
                acc[ii].z += sv * vv.z;
                acc[ii].w += sv * vv.w;
            }
        }
        __syncthreads();
    }

    #pragma unroll
    for (int ii = 0; ii < 4; ++ii)
        *(float4*)&ob[(size_t)(i0 + ig * 4 + ii) * DD + dg * 4] = acc[ii];
}

extern "C" void kernel_launch(void* const* d_in, const int* in_sizes, int n_in,
                              void* d_out, int out_size, void* d_ws, size_t ws_size,
                              hipStream_t stream) {
    const float* q    = (const float*)d_in[0];
    const float* k    = (const float*)d_in[1];
    const float* v    = (const float*)d_in[2];
    const int*   mask = (const int*)d_in[3];

    float* out   = (float*)d_out;
    float* score = out + (size_t)NB * NH * LSEQ * DD;  // output 1 region

    dim3 g1(LSEQ / BJ, LSEQ / BQ, NB);   // 32 x 128 x 2
    qk_softmax_kernel<<<g1, 256, 0, stream>>>(q, k, mask, score);

    dim3 g2(LSEQ / TI2, NH, NB);         // 32 x 16 x 2
    pv_kernel<<<g2, 256, 0, stream>>>(score, v, out);
}

// Round 3
// 514.694 us; speedup vs baseline: 3.0327x; 3.0327x over previous
//
#include <hip/hip_runtime.h>
#include <math.h>

#define NB 2
#define NH 16
#define LSEQ 2048
#define DD 64
#define HSZ (LSEQ*DD)            // 131072 elements per (b,h)
#define NELEM (NB*NH*HSZ)        // 4194304 per tensor

typedef _Float16 half_t;
typedef _Float16 f16x4 __attribute__((ext_vector_type(4)));
typedef _Float16 f16x8 __attribute__((ext_vector_type(8)));
typedef float    f32x4 __attribute__((ext_vector_type(4)));

// ---------------- K0a: q f32 -> f16 ----------------
__global__ __launch_bounds__(256) void convert_q(
    const float* __restrict__ q, half_t* __restrict__ qh)
{
    const int n4 = NELEM / 4;
    for (int gid = blockIdx.x * 256 + threadIdx.x; gid < n4; gid += gridDim.x * 256) {
        float4 x = ((const float4*)q)[gid];
        f16x4 y;
        y[0] = (half_t)x.x; y[1] = (half_t)x.y; y[2] = (half_t)x.z; y[3] = (half_t)x.w;
        ((f16x4*)qh)[gid] = y;
    }
}

// ---------------- K0b: transpose+convert K-view and V ----------------
// z=0: per (b,h) k-block viewed [64][2048] f32  -> kt [2048][64] f16
// z=1: per (b,h) v-block        [2048][64] f32  -> vt [64][2048] f16
__global__ __launch_bounds__(256) void transpose_cvt(
    const float* __restrict__ k, const float* __restrict__ v,
    half_t* __restrict__ kt, half_t* __restrict__ vt)
{
    __shared__ half_t lds[64][72];   // [c_local][r_local], padded
    const int tid = threadIdx.x;
    const int bh  = blockIdx.y;
    const int t64 = blockIdx.x;      // 0..31
    const float* src; half_t* dst; int C, R, r0, c0;
    if (blockIdx.z == 0) {
        src = k + (size_t)bh * HSZ; dst = kt + (size_t)bh * HSZ;
        R = 64; C = LSEQ; r0 = 0; c0 = t64 * 64;
    } else {
        src = v + (size_t)bh * HSZ; dst = vt + (size_t)bh * HSZ;
        R = LSEQ; C = 64; r0 = t64 * 64; c0 = 0;
    }
    const int rr = tid & 63, w4 = tid >> 6;
    #pragma unroll
    for (int qq = 0; qq < 4; ++qq) {
        float4 x = *(const float4*)&src[(size_t)(r0 + rr) * C + c0 + w4 * 16 + qq * 4];
        lds[w4 * 16 + qq * 4 + 0][rr] = (half_t)x.x;
        lds[w4 * 16 + qq * 4 + 1][rr] = (half_t)x.y;
        lds[w4 * 16 + qq * 4 + 2][rr] = (half_t)x.z;
        lds[w4 * 16 + qq * 4 + 3][rr] = (half_t)x.w;
    }
    __syncthreads();
    #pragma unroll
    for (int p = 0; p < 2; ++p) {
        const int id = tid + p * 256;
        const int cl = id >> 3, rc = id & 7;
        f16x8 y = *(const f16x8*)&lds[cl][rc * 8];
        *(f16x8*)&dst[(size_t)(c0 + cl) * R + r0 + rc * 8] = y;
    }
}

// ---------------- K1: QK(view) + mask + softmax over heads ----------------
// block = (b, i0:32, j0:32, all 16 heads); 4 waves, wave w -> quadrant
// (is=w>>1, jb=w&1). All-register, no LDS, no barriers.
// MFMA conventions: A/B frags = 8 contiguous k-elems at k=(lane>>4)*8 (same
// convention both operands => k-permutation-invariant). C/D: col=lane&15,
// row=(lane>>4)*4+reg  [HW-verified m89/m91].
__global__ __launch_bounds__(256) void qk_softmax_mfma(
    const half_t* __restrict__ qh, const half_t* __restrict__ kt,
    const int* __restrict__ mask, float* __restrict__ score)
{
    const int tid = threadIdx.x, w = tid >> 6, lane = tid & 63;
    const int is = w >> 1, jb = w & 1;
    const int j0 = blockIdx.x * 32, i0 = blockIdx.y * 32, b = blockIdx.z;
    const int g8 = (lane >> 4) * 8, n16 = lane & 15;
    const int irow = i0 + is * 16 + n16;     // A-frag row
    const int jcol = j0 + jb * 16 + n16;     // B-frag col (kt row)
    const size_t hb0 = (size_t)b * NH;

    f32x4 acc[NH];
    #pragma unroll
    for (int h = 0; h < NH; ++h) { acc[h][0] = 0.f; acc[h][1] = 0.f; acc[h][2] = 0.f; acc[h][3] = 0.f; }

    #pragma unroll
    for (int h = 0; h < NH; ++h) {
        const half_t* qp = qh + (hb0 + h) * (size_t)HSZ + (size_t)irow * DD;
        const half_t* kp = kt + (hb0 + h) * (size_t)HSZ + (size_t)jcol * DD;
        f16x8 a0 = *(const f16x8*)(qp + g8);
        f16x8 a1 = *(const f16x8*)(qp + 32 + g8);
        f16x8 b0 = *(const f16x8*)(kp + g8);
        f16x8 b1 = *(const f16x8*)(kp + 32 + g8);
        acc[h] = __builtin_amdgcn_mfma_f32_16x16x32_f16(a0, b0, acc[h], 0, 0, 0);
        acc[h] = __builtin_amdgcn_mfma_f32_16x16x32_f16(a1, b1, acc[h], 0, 0, 0);
    }

    // C rows for this lane: i0 + is*16 + (lane>>4)*4 + r ; col = jcol
    const int crow0 = i0 + is * 16 + (lane >> 4) * 4;
    #pragma unroll
    for (int r = 0; r < 4; ++r) {
        const int m = mask[((size_t)b * LSEQ + crow0 + r) * LSEQ + jcol];
        if (m == 0) {
            #pragma unroll
            for (int h = 0; h < NH; ++h) acc[h][r] = 0.0625f;   // exact 1/16
        } else {
            float mx = acc[0][r];
            #pragma unroll
            for (int h = 1; h < NH; ++h) mx = fmaxf(mx, acc[h][r]);
            float s = 0.f;
            #pragma unroll
            for (int h = 0; h < NH; ++h) {
                float e = __expf(0.125f * (acc[h][r] - mx));
                acc[h][r] = e;
                s += e;
            }
            const float inv = 1.0f / s;
            #pragma unroll
            for (int h = 0; h < NH; ++h) acc[h][r] *= inv;
        }
    }
    #pragma unroll
    for (int h = 0; h < NH; ++h)
        #pragma unroll
        for (int r = 0; r < 4; ++r)
            score[((hb0 + h) * LSEQ + crow0 + r) * LSEQ + jcol] = acc[h][r];
}

// ---------------- K2: out = score @ v via MFMA ----------------
// block = (b,h, 64 i-rows); wave w -> rows i0+w*16. B-frags straight from
// pre-transposed vt (global, L2-resident). No LDS, no barriers.
__global__ __launch_bounds__(256) void pv_mfma(
    const float* __restrict__ score, const half_t* __restrict__ vt,
    float* __restrict__ out)
{
    const int tid = threadIdx.x, w = tid >> 6, lane = tid & 63;
    const int i0 = blockIdx.x * 64;
    const size_t bh = (size_t)blockIdx.z * NH + blockIdx.y;
    const float*  sb = score + bh * (size_t)LSEQ * LSEQ;
    const half_t* vb = vt + bh * (size_t)HSZ;
    float*        ob = out + bh * (size_t)HSZ;
    const int g8 = (lane >> 4) * 8, n16 = lane & 15;
    const int irow = i0 + w * 16 + n16;

    f32x4 acc[4];
    #pragma unroll
    for (int ds = 0; ds < 4; ++ds) { acc[ds][0] = 0.f; acc[ds][1] = 0.f; acc[ds][2] = 0.f; acc[ds][3] = 0.f; }

    const float* sp0 = sb + (size_t)irow * LSEQ + g8;

    #pragma unroll 2
    for (int t = 0; t < 64; ++t) {
        float4 sA = *(const float4*)(sp0 + t * 32);
        float4 sB = *(const float4*)(sp0 + t * 32 + 4);
        f16x8 a8;
        a8[0] = (half_t)sA.x; a8[1] = (half_t)sA.y; a8[2] = (half_t)sA.z; a8[3] = (half_t)sA.w;
        a8[4] = (half_t)sB.x; a8[5] = (half_t)sB.y; a8[6] = (half_t)sB.z; a8[7] = (half_t)sB.w;
        #pragma unroll
        for (int ds = 0; ds < 4; ++ds) {
            f16x8 b8 = *(const f16x8*)(vb + (size_t)(ds * 16 + n16) * LSEQ + t * 32 + g8);
            acc[ds] = __builtin_amdgcn_mfma_f32_16x16x32_f16(a8, b8, acc[ds], 0, 0, 0);
        }
    }
    const int orow0 = i0 + w * 16 + (lane >> 4) * 4;
    #pragma unroll
    for (int ds = 0; ds < 4; ++ds)
        #pragma unroll
        for (int r = 0; r < 4; ++r)
            ob[(size_t)(orow0 + r) * DD + ds * 16 + n16] = acc[ds][r];
}

extern "C" void kernel_launch(void* const* d_in, const int* in_sizes, int n_in,
                              void* d_out, int out_size, void* d_ws, size_t ws_size,
                              hipStream_t stream) {
    const float* q    = (const float*)d_in[0];
    const float* k    = (const float*)d_in[1];
    const float* v    = (const float*)d_in[2];
    const int*   mask = (const int*)d_in[3];

    float* out   = (float*)d_out;
    float* score = out + (size_t)NB * NH * LSEQ * DD;

    half_t* qh = (half_t*)d_ws;          // 8 MB
    half_t* kt = qh + NELEM;             // 8 MB  kt[b,h][j][d]
    half_t* vt = kt + NELEM;             // 8 MB  vt[b,h][d][j]

    convert_q<<<2048, 256, 0, stream>>>(q, qh);
    transpose_cvt<<<dim3(32, NB * NH, 2), 256, 0, stream>>>(k, v, kt, vt);
    qk_softmax_mfma<<<dim3(LSEQ / 32, LSEQ / 32, NB), 256, 0, stream>>>(qh, kt, mask, score);
    pv_mfma<<<dim3(LSEQ / 64, NH, NB), 256, 0, stream>>>(score, vt, out);
}